// Round 9
// baseline (3734.430 us; speedup 1.0000x reference)
//
#include <hip/hip_runtime.h>

typedef short short8 __attribute__((ext_vector_type(8)));
typedef float f32x4 __attribute__((ext_vector_type(4)));
typedef unsigned short u16;
typedef unsigned int u32;

#define C64 64
#define HWp (512*512)
#define NWG 128    // 4 images x 32 bands of 16 rows
#define PR 72      // LDS row stride in u16 (144 B)
#define NROW 32    // rows computed per step (2 MFMA M-tiles)
#define SLOTS 34   // state window: absrows a-8 .. a+25
#define T7 7       // columns per epoch (511 = 7*73)
#define NEP 73

struct Ws {
  int flags[NWG][32];        // one 128B line per band
  u32 haloT[NWG][2][8*64];   // band's rows absr a..a+7 (m=7..14), f32 bits
  u32 haloB[NWG][2][7*64];   // band's rows absr a+9..a+15 (m=16..22), f32 bits
};

__device__ __forceinline__ u16 f2bf(float f){
  u32 u = __float_as_uint(f);
  u += 0x7fffu + ((u >> 16) & 1u);
  return (u16)(u >> 16);
}
__device__ __forceinline__ float bf2f(u16 h){ return __uint_as_float(((u32)h) << 16); }
__device__ __forceinline__ f32x4 splat4(float x){ f32x4 v = {x,x,x,x}; return v; }
__device__ __forceinline__ float sigm(float x){ return 1.f/(1.f + __expf(-x)); }
__device__ __forceinline__ float tanh_(float x){ float e = __expf(2.f*x); return 1.f - 2.f/(e + 1.f); }

#define MFMA16(a,b,c) __builtin_amdgcn_mfma_f32_16x16x32_bf16(a,b,c,0,0,0)
#define ATOM_ST(p,v) __hip_atomic_store((p),(v),__ATOMIC_RELAXED,__HIP_MEMORY_SCOPE_AGENT)
#define ATOM_LD(p)   __hip_atomic_load((p),__ATOMIC_RELAXED,__HIP_MEMORY_SCOPE_AGENT)
// merged 3-term hi/lo product (r5/r8-verified numerics; single accumulator chain)
#define DOT3(acc, XH, XL, WH, WL) \
  acc = MFMA16(XH, WH, acc); acc = MFMA16(XL, WH, acc); acc = MFMA16(XH, WL, acc);

__global__ void reset_flags(int* flags) {
  if (threadIdx.x < NWG) flags[threadIdx.x * 32] = -1;
}

__global__ void
__attribute__((amdgpu_flat_work_group_size(512, 512), amdgpu_waves_per_eu(2, 2)))
gru_scan(const float* __restrict__ feat,
         const float* __restrict__ w_ih,
         const float* __restrict__ w_hh,
         const float* __restrict__ b_ih,
         const float* __restrict__ b_hh,
         float* __restrict__ out,
         Ws* __restrict__ ws)
{
  // ping-pong state: slot s = absrow (a-8+s), hi/lo bf16 planes
  __shared__ __align__(16) u16 sh[2*SLOTS*PR], sl[2*SLOTS*PR];
  // ping-pong current feat column, rows m=0..31 (absrow a-7+m)
  __shared__ __align__(16) u16 uh[2*NROW*PR], ul[2*NROW*PR];
  // output stage: [owned row 0..15][col 0..6][ch 0..63] bf16
  __shared__ u16 ostage[16*T7*64];

  const int tid  = threadIdx.x;
  const int wg   = blockIdx.x;
  const int b    = wg >> 5;
  const int kband= wg & 31;
  const int a    = kband * 16;          // first owned row
  const int lane = tid & 63;
  const int wid  = tid >> 6;            // 0..7
  const int rg   = wid >> 2;            // M-tile of this wave (0 or 1)
  const int q    = wid & 3;             // ch-quarter
  const int ln16 = lane & 15;
  const int kgrp = lane >> 4;
  const int ch   = q*16 + ln16;         // output channel of this thread

  // ---- weights (hi+lo) in registers: 192 VGPR ----
  short8 BihH[3][6], BihL[3][6], BhhH[3][2], BhhL[3][2];
#pragma unroll
  for (int g = 0; g < 3; ++g) {
    const int n = g*64 + ch;
#pragma unroll
    for (int kk = 0; kk < 6; ++kk) {
      short8 vh, vl;
#pragma unroll
      for (int j = 0; j < 8; ++j) {
        float wv = w_ih[n*192 + kk*32 + kgrp*8 + j];
        u16 h = f2bf(wv); vh[j] = (short)h; vl[j] = (short)f2bf(wv - bf2f(h));
      }
      BihH[g][kk] = vh; BihL[g][kk] = vl;
    }
#pragma unroll
    for (int kt = 0; kt < 2; ++kt) {
      short8 vh, vl;
#pragma unroll
      for (int j = 0; j < 8; ++j) {
        float wv = w_hh[n*64 + kt*32 + kgrp*8 + j];
        u16 h = f2bf(wv); vh[j] = (short)h; vl[j] = (short)f2bf(wv - bf2f(h));
      }
      BhhH[g][kt] = vh; BhhL[g][kt] = vl;
    }
  }
  const float biasR  = b_ih[ch]       + b_hh[ch];
  const float biasZ  = b_ih[64 + ch]  + b_hh[64 + ch];
  const float biasI  = b_ih[128 + ch];
  const float biasHn = b_hh[128 + ch];

  // ---- loader mapping: thread owns 4 rows of one channel ----
  const int lch = tid & 63;
  const int lr0 = (tid >> 6) * 4;
  const float* fbase = feat + (size_t)(b*C64 + lch)*HWp;

  float cv[4];   // per-step staged next column

  // ---- init ----
  for (int i = tid; i < 2*SLOTS*PR; i += 512) { sh[i] = 0; sl[i] = 0; }
  __syncthreads();
  // column 0 -> state buf0 + out passthrough; column 1 -> u buf0
#pragma unroll
  for (int i = 0; i < 4; ++i) {
    const int m = lr0 + i, absr = a - 7 + m;
    if ((unsigned)absr < 512u) {
      float v = fbase[(size_t)absr*512];
      u16 h_ = f2bf(v);
      sh[(m+1)*PR + lch] = h_;
      sl[(m+1)*PR + lch] = f2bf(v - bf2f(h_));
      if (m >= 7 && m < 23) out[(size_t)(b*C64 + lch)*HWp + (size_t)absr*512] = v;
      float v1 = fbase[(size_t)absr*512 + 1];
      u16 h1 = f2bf(v1);
      uh[m*PR + lch] = h1;
      ul[m*PR + lch] = f2bf(v1 - bf2f(h1));
    } else {
      uh[m*PR + lch] = 0; ul[m*PR + lch] = 0;
    }
  }
  __syncthreads();

  // ---- epoch loop ----
  for (int e = 0; e < NEP; ++e) {
    const int par = e & 1;
#pragma unroll 1
    for (int d = 0; d < T7; ++d) {
      const int w = e*T7 + 1 + d;
      const int p = (e + d) & 1;          // parity of step n=7e+d
      const u16* shp = sh + p*SLOTS*PR;
      const u16* slp = sl + p*SLOTS*PR;
      const u16* uhp = uh + p*NROW*PR;
      const u16* ulp = ul + p*NROW*PR;
      u16* shn = sh + (p^1)*SLOTS*PR;
      u16* sln = sl + (p^1)*SLOTS*PR;
      u16* uhn = uh + (p^1)*NROW*PR;
      u16* uln = ul + (p^1)*NROW*PR;

      // issue next-column loads early (d=6's load primes the next epoch)
      {
        const int wn = (w < 511) ? w + 1 : 511;
#pragma unroll
        for (int i = 0; i < 4; ++i) {
          const int absr = a - 7 + lr0 + i;
          cv[i] = ((unsigned)absr < 512u) ? fbase[(size_t)absr*512 + wn] : 0.f;
        }
      }

      // ---- compute: ONE M-tile (t = rg), single-chain accumulators ----
      float hnv[4];
      {
        const int t = rg;
        f32x4 aR = splat4(biasR), aZ = splat4(biasZ);
        f32x4 aI = splat4(biasI), aH = splat4(biasHn);
        short8 Xh[2], Xl[2];
#pragma unroll
        for (int kt = 0; kt < 2; ++kt) {
          const int ro = (t*16 + ln16)*PR + kt*32 + kgrp*8;
          Xh[kt] = *(const short8*)&uhp[ro];
          Xl[kt] = *(const short8*)&ulp[ro];
        }
#pragma unroll
        for (int kk = 0; kk < 6; ++kk) {
          const int ro = (t*16 + ln16 + (kk>>1))*PR + (kk&1)*32 + kgrp*8;
          short8 Ah = *(const short8*)&shp[ro];
          short8 Al = *(const short8*)&slp[ro];
          DOT3(aR, Ah, Al, BihH[0][kk], BihL[0][kk]);
          DOT3(aZ, Ah, Al, BihH[1][kk], BihL[1][kk]);
          DOT3(aI, Ah, Al, BihH[2][kk], BihL[2][kk]);
        }
#pragma unroll
        for (int kt = 0; kt < 2; ++kt) {
          DOT3(aR, Xh[kt], Xl[kt], BhhH[0][kt], BhhL[0][kt]);
          DOT3(aZ, Xh[kt], Xl[kt], BhhH[1][kt], BhhL[1][kt]);
          DOT3(aH, Xh[kt], Xl[kt], BhhH[2][kt], BhhL[2][kt]);
        }
#pragma unroll
        for (int j = 0; j < 4; ++j) {
          const int m = t*16 + kgrp*4 + j;
          float r = sigm(aR[j]);
          float z = sigm(aZ[j]);
          float nn = tanh_(aI[j] + r * aH[j]);
          float cur = bf2f(uhp[m*PR + ch]) + bf2f(ulp[m*PR + ch]);
          hnv[j] = (1.f - z)*nn + z*cur;
        }
      }

      // ---- writeback to the other buffers + ostage (+halo sends at d=6) ----
#pragma unroll
      for (int j = 0; j < 4; ++j) {
        const int m = rg*16 + kgrp*4 + j;
        const int absr = a - 7 + m;
        const float v = hnv[j];
        if ((unsigned)absr < 512u) {     // keeps out-of-image slots zero
          u16 h_ = f2bf(v);
          shn[(m+1)*PR + ch] = h_;
          sln[(m+1)*PR + ch] = f2bf(v - bf2f(h_));
        }
        if (m >= 7 && m < 23)
          ostage[((m-7)*T7 + d)*64 + ch] = f2bf(v);
        if (d == T7-1 && e < NEP-1) {    // epoch-boundary halo send (exact f32)
          if (m >= 7 && m <= 14)         // absr a..a+7
            ATOM_ST(&ws->haloT[wg][par][(m-7)*64 + ch], __float_as_uint(v));
          if (m >= 16 && m <= 22)        // absr a+9..a+15
            ATOM_ST(&ws->haloB[wg][par][(m-16)*64 + ch], __float_as_uint(v));
        }
      }
      if (d < T7-1) {
        // u[p^1] <- staged column
#pragma unroll
        for (int i = 0; i < 4; ++i) {
          const int m = lr0 + i;
          u16 h_ = f2bf(cv[i]);
          uhn[m*PR + lch] = h_;
          uln[m*PR + lch] = f2bf(cv[i] - bf2f(h_));
        }
        __syncthreads();                 // the single per-step barrier
      }
    }

    // ---- epoch boundary ----
    asm volatile("s_waitcnt vmcnt(0)" ::: "memory");  // drain halo sends
    __syncthreads();
    if (e < NEP-1 && tid == 0) ATOM_ST(&ws->flags[wg][0], e);

    if (wid >= 4) {
      // flush epoch's 7 output columns (bf16 stage -> f32 global), 256 threads
      const int thr = tid - 256;
#pragma unroll 1
      for (int i = 0; i < 4; ++i) {
        const int ci = thr + 256*i;
        const int c = ci & 63, row = ci >> 6;          // row in [0,16)
        float* go = out + (size_t)(b*C64 + c)*HWp + (size_t)(a + row)*512 + (e*T7 + 1);
#pragma unroll
        for (int dc = 0; dc < T7; ++dc)
          go[dc] = bf2f(ostage[(row*T7 + dc)*64 + c]);
      }
    } else if (e < NEP-1) {
      const int pn = (e + 1) & 1;
      u16* shx = sh + pn*SLOTS*PR;
      u16* slx = sl + pn*SLOTS*PR;
      if (wid == 1 && kband > 0) {        // top halo <- up-neighbor's haloB
        int f = -1, guard = 0;
        while (f < e && ++guard < (1<<17)) {
          if (lane == 0) f = ATOM_LD(&ws->flags[wg-1][0]);
          f = __shfl(f, 0);
          if (f < e) __builtin_amdgcn_s_sleep(1);
        }
        asm volatile("" ::: "memory");
#pragma unroll
        for (int i = 0; i < 7; ++i) {     // absrow a-7+i -> slot 1+i
          float v = __uint_as_float(ATOM_LD(&ws->haloB[wg-1][par][i*64 + lane]));
          u16 h_ = f2bf(v);
          shx[(1+i)*PR + lane] = h_;
          slx[(1+i)*PR + lane] = f2bf(v - bf2f(h_));
        }
      }
      if (wid == 2 && kband < 31) {       // bottom halo <- down-neighbor's haloT
        int f = -1, guard = 0;
        while (f < e && ++guard < (1<<17)) {
          if (lane == 0) f = ATOM_LD(&ws->flags[wg+1][0]);
          f = __shfl(f, 0);
          if (f < e) __builtin_amdgcn_s_sleep(1);
        }
        asm volatile("" ::: "memory");
#pragma unroll
        for (int i = 0; i < 8; ++i) {     // absrow a+16+i -> slot 24+i
          float v = __uint_as_float(ATOM_LD(&ws->haloT[wg+1][par][i*64 + lane]));
          u16 h_ = f2bf(v);
          shx[(24+i)*PR + lane] = h_;
          slx[(24+i)*PR + lane] = f2bf(v - bf2f(h_));
        }
      }
    }

    if (e < NEP-1) {
      // prime u[(e+1)&1] from the d=6 staged column (already in cv)
      const int pn = (e + 1) & 1;
      u16* uhx = uh + pn*NROW*PR;
      u16* ulx = ul + pn*NROW*PR;
#pragma unroll
      for (int i = 0; i < 4; ++i) {
        const int m = lr0 + i;
        u16 h_ = f2bf(cv[i]);
        uhx[m*PR + lch] = h_;
        ulx[m*PR + lch] = f2bf(cv[i] - bf2f(h_));
      }
    }
    __syncthreads();   // halos + u primed + flush done before next epoch's steps
  }
}

extern "C" void kernel_launch(void* const* d_in, const int* in_sizes, int n_in,
                              void* d_out, int out_size, void* d_ws, size_t ws_size,
                              hipStream_t stream) {
  const float* feat = (const float*)d_in[0];
  const float* wih  = (const float*)d_in[1];
  const float* whh  = (const float*)d_in[2];
  const float* bih  = (const float*)d_in[3];
  const float* bhh  = (const float*)d_in[4];
  float* out = (float*)d_out;
  Ws* ws = (Ws*)d_ws;

  reset_flags<<<1, NWG, 0, stream>>>((int*)ws->flags);
  gru_scan<<<NWG, 512, 0, stream>>>(feat, wih, whh, bih, bhh, out, ws);
}

// Round 10
// 2094.916 us; speedup vs baseline: 1.7826x; 1.7826x over previous
//
#include <hip/hip_runtime.h>

typedef short short8 __attribute__((ext_vector_type(8)));
typedef float f32x4 __attribute__((ext_vector_type(4)));
typedef unsigned short u16;
typedef unsigned int u32;

#define C64 64
#define HWp (512*512)
#define NWG 256    // 4 images x 64 bands of 8 rows
#define PR 72      // LDS row stride in u16 (144 B)
#define NROW 16    // rows computed per step (1 MFMA M-tile)
#define SLOTS 18   // state window: absrows a-4 .. a+13 (slot s = absr-(a-4))
#define T3 3       // columns per epoch
#define NEP 171    // ceil(511/3)

struct Ws {
  int flags[NWG][32];        // one 128B line per band-chain node
  u32 haloT[NWG][2][4*64];   // band's rows absr a..a+3   (m=3..6),  f32 bits
  u32 haloB[NWG][2][3*64];   // band's rows absr a+5..a+7 (m=8..10), f32 bits
};

__device__ __forceinline__ u16 f2bf(float f){
  u32 u = __float_as_uint(f);
  u += 0x7fffu + ((u >> 16) & 1u);
  return (u16)(u >> 16);
}
__device__ __forceinline__ float bf2f(u16 h){ return __uint_as_float(((u32)h) << 16); }
__device__ __forceinline__ f32x4 splat4(float x){ f32x4 v = {x,x,x,x}; return v; }
__device__ __forceinline__ float sigm(float x){ return 1.f/(1.f + __expf(-x)); }
__device__ __forceinline__ float tanh_(float x){ float e = __expf(2.f*x); return 1.f - 2.f/(e + 1.f); }

#define MFMA16(a,b,c) __builtin_amdgcn_mfma_f32_16x16x32_bf16(a,b,c,0,0,0)
#define ATOM_ST(p,v) __hip_atomic_store((p),(v),__ATOMIC_RELAXED,__HIP_MEMORY_SCOPE_AGENT)
#define ATOM_LD(p)   __hip_atomic_load((p),__ATOMIC_RELAXED,__HIP_MEMORY_SCOPE_AGENT)
// merged 3-term hi/lo product (r5/r8-verified numerics)
#define DOT3(acc, XH, XL, WH, WL) \
  acc = MFMA16(XH, WH, acc); acc = MFMA16(XL, WH, acc); acc = MFMA16(XH, WL, acc);

__global__ void reset_flags(int* flags) {
  if (threadIdx.x < NWG) flags[threadIdx.x * 32] = -1;
}

__global__ __launch_bounds__(256, 1)
void gru_scan(const float* __restrict__ feat,
              const float* __restrict__ w_ih,
              const float* __restrict__ w_hh,
              const float* __restrict__ b_ih,
              const float* __restrict__ b_hh,
              float* __restrict__ out,
              Ws* __restrict__ ws)
{
  // ping-pong state: slot s = absrow (a-4+s), hi/lo bf16 planes
  __shared__ __align__(16) u16 sh[2*SLOTS*PR], sl[2*SLOTS*PR];
  // ping-pong current feat column, rows m=0..15 (absrow a-3+m)
  __shared__ __align__(16) u16 uh[2*NROW*PR], ul[2*NROW*PR];

  const int tid  = threadIdx.x;
  const int wgid = blockIdx.x;
  // XCD swizzle: consecutive band-chain ids g share an XCD (31/32 halo links intra-XCD)
  const int g    = (wgid & 7) * 32 + (wgid >> 3);
  const int b    = g >> 6;
  const int kband= g & 63;
  const int a    = kband * 8;           // first owned row
  const int lane = tid & 63;
  const int wid  = tid >> 6;            // 0..3 = ch-quarter
  const int ln16 = lane & 15;
  const int kgrp = lane >> 4;
  const int ch   = wid*16 + ln16;       // output channel of this thread

  // ---- weights (hi+lo) in registers: 192 VGPR ----
  short8 BihH[3][6], BihL[3][6], BhhH[3][2], BhhL[3][2];
#pragma unroll
  for (int gg = 0; gg < 3; ++gg) {
    const int n = gg*64 + ch;
#pragma unroll
    for (int kk = 0; kk < 6; ++kk) {
      short8 vh, vl;
#pragma unroll
      for (int j = 0; j < 8; ++j) {
        float wv = w_ih[n*192 + kk*32 + kgrp*8 + j];
        u16 h = f2bf(wv); vh[j] = (short)h; vl[j] = (short)f2bf(wv - bf2f(h));
      }
      BihH[gg][kk] = vh; BihL[gg][kk] = vl;
    }
#pragma unroll
    for (int kt = 0; kt < 2; ++kt) {
      short8 vh, vl;
#pragma unroll
      for (int j = 0; j < 8; ++j) {
        float wv = w_hh[n*64 + kt*32 + kgrp*8 + j];
        u16 h = f2bf(wv); vh[j] = (short)h; vl[j] = (short)f2bf(wv - bf2f(h));
      }
      BhhH[gg][kt] = vh; BhhL[gg][kt] = vl;
    }
  }
  const float biasR  = b_ih[ch]       + b_hh[ch];
  const float biasZ  = b_ih[64 + ch]  + b_hh[64 + ch];
  const float biasI  = b_ih[128 + ch];
  const float biasHn = b_hh[128 + ch];

  // ---- loader mapping: thread owns 4 u-rows of one channel ----
  const int lch = tid & 63;
  const int lr0 = (tid >> 6) * 4;
  const float* fbase = feat + (size_t)(b*C64 + lch)*HWp;
  float*       obase = out  + (size_t)(b*C64 + lch)*HWp;

  float cv[4];   // per-step staged next column

  // ---- init ----
  for (int i = tid; i < 2*SLOTS*PR; i += 256) { sh[i] = 0; sl[i] = 0; }
  __syncthreads();
  // feat col 0 -> state buf0 (full window, slots 0..17) + out passthrough (owned s 4..11)
#pragma unroll
  for (int i = 0; i < 5; ++i) {
    const int s = (tid >> 6) + 4*i;       // 0..19
    if (s < SLOTS) {
      const int absr = a - 4 + s;
      if ((unsigned)absr < 512u) {
        float v = fbase[(size_t)absr*512];
        u16 h_ = f2bf(v);
        sh[s*PR + lch] = h_;
        sl[s*PR + lch] = f2bf(v - bf2f(h_));
        if (s >= 4 && s <= 11) obase[(size_t)absr*512] = v;
      }
    }
  }
  // feat col 1 -> u buf0 (rows m 0..15, absr a-3+m)
#pragma unroll
  for (int i = 0; i < 4; ++i) {
    const int m = lr0 + i, absr = a - 3 + m;
    float v = ((unsigned)absr < 512u) ? fbase[(size_t)absr*512 + 1] : 0.f;
    u16 h_ = f2bf(v);
    uh[m*PR + lch] = h_;
    ul[m*PR + lch] = f2bf(v - bf2f(h_));
  }
  __syncthreads();

  // ---- epoch loop ----
  for (int e = 0; e < NEP; ++e) {
    const int par = e & 1;
    int dlast = 510 - 3*e; if (dlast > T3-1) dlast = T3-1;
#pragma unroll 1
    for (int d = 0; d <= dlast; ++d) {
      const int w = 3*e + 1 + d;
      const int p = (e + d) & 1;          // parity of step n=3e+d
      const u16* shp = sh + p*SLOTS*PR;
      const u16* slp = sl + p*SLOTS*PR;
      const u16* uhp = uh + p*NROW*PR;
      const u16* ulp = ul + p*NROW*PR;
      u16* shn = sh + (p^1)*SLOTS*PR;
      u16* sln = sl + (p^1)*SLOTS*PR;
      u16* uhn = uh + (p^1)*NROW*PR;
      u16* uln = ul + (p^1)*NROW*PR;

      // issue next-column loads early
      {
        const int wn = (w < 511) ? w + 1 : 511;
#pragma unroll
        for (int i = 0; i < 4; ++i) {
          const int absr = a - 3 + lr0 + i;
          cv[i] = ((unsigned)absr < 512u) ? fbase[(size_t)absr*512 + wn] : 0.f;
        }
      }

      // ---- compute: ONE M-tile ----
      float hnv[4];
      {
        f32x4 aR = splat4(biasR), aZ = splat4(biasZ);
        f32x4 aI = splat4(biasI), aH = splat4(biasHn);
        short8 Xh[2], Xl[2];
#pragma unroll
        for (int kt = 0; kt < 2; ++kt) {
          const int ro = ln16*PR + kt*32 + kgrp*8;
          Xh[kt] = *(const short8*)&uhp[ro];
          Xl[kt] = *(const short8*)&ulp[ro];
        }
#pragma unroll
        for (int kk = 0; kk < 6; ++kk) {
          // output row m=ln16 reads state slots ln16 + {0,1,2}
          const int ro = (ln16 + (kk>>1))*PR + (kk&1)*32 + kgrp*8;
          short8 Ah = *(const short8*)&shp[ro];
          short8 Al = *(const short8*)&slp[ro];
          DOT3(aR, Ah, Al, BihH[0][kk], BihL[0][kk]);
          DOT3(aZ, Ah, Al, BihH[1][kk], BihL[1][kk]);
          DOT3(aI, Ah, Al, BihH[2][kk], BihL[2][kk]);
        }
#pragma unroll
        for (int kt = 0; kt < 2; ++kt) {
          DOT3(aR, Xh[kt], Xl[kt], BhhH[0][kt], BhhL[0][kt]);
          DOT3(aZ, Xh[kt], Xl[kt], BhhH[1][kt], BhhL[1][kt]);
          DOT3(aH, Xh[kt], Xl[kt], BhhH[2][kt], BhhL[2][kt]);
        }
#pragma unroll
        for (int j = 0; j < 4; ++j) {
          const int m = kgrp*4 + j;
          float r = sigm(aR[j]);
          float z = sigm(aZ[j]);
          float nn = tanh_(aI[j] + r * aH[j]);
          float cur = bf2f(uhp[m*PR + ch]) + bf2f(ulp[m*PR + ch]);
          hnv[j] = (1.f - z)*nn + z*cur;
        }
      }

      // ---- writeback: state-next + direct out + (halo sends at epoch end) ----
#pragma unroll
      for (int j = 0; j < 4; ++j) {
        const int m = kgrp*4 + j;          // slot s = m+1
        const int absr = a - 3 + m;
        const float v = hnv[j];
        if ((unsigned)absr < 512u) {       // keeps out-of-image slots zero
          u16 h_ = f2bf(v);
          shn[(m+1)*PR + ch] = h_;
          sln[(m+1)*PR + ch] = f2bf(v - bf2f(h_));
          if (m >= 3 && m <= 10)           // owned row: direct global store
            out[(size_t)(b*C64 + ch)*HWp + (size_t)absr*512 + w] = v;
        }
        if (d == dlast && e < NEP-1) {     // epoch-boundary halo send (exact f32)
          if (m >= 3 && m <= 6)            // absr a..a+3
            ATOM_ST(&ws->haloT[g][par][(m-3)*64 + ch], __float_as_uint(v));
          if (m >= 8 && m <= 10)           // absr a+5..a+7
            ATOM_ST(&ws->haloB[g][par][(m-8)*64 + ch], __float_as_uint(v));
        }
      }
      // u[p^1] <- staged next column (uniform every step)
#pragma unroll
      for (int i = 0; i < 4; ++i) {
        const int m = lr0 + i;
        u16 h_ = f2bf(cv[i]);
        uhn[m*PR + lch] = h_;
        uln[m*PR + lch] = f2bf(cv[i] - bf2f(h_));
      }
      if (d < dlast) __syncthreads();      // per-step barrier
    }

    // ---- epoch boundary ----
    asm volatile("s_waitcnt vmcnt(0)" ::: "memory");  // halo sends drained (per wave)
    __syncthreads();                                  // all waves drained + LDS wb done
    if (e < NEP-1) {
      if (tid == 0) ATOM_ST(&ws->flags[g][0], e);
      const int pn = (e + 1) & 1;                     // parity of next epoch's first step
      u16* shx = sh + pn*SLOTS*PR;
      u16* slx = sl + pn*SLOTS*PR;
      if (wid == 1 && kband > 0) {        // top margin <- up-neighbor's haloB
        int f = -1, guard = 0;
        while (f < e && ++guard < (1<<17)) {
          if (lane == 0) f = ATOM_LD(&ws->flags[g-1][0]);
          f = __shfl(f, 0);
          if (f < e) __builtin_amdgcn_s_sleep(1);
        }
        asm volatile("" ::: "memory");
#pragma unroll
        for (int i = 0; i < 3; ++i) {     // absr a-3+i -> slot 1+i
          float v = __uint_as_float(ATOM_LD(&ws->haloB[g-1][par][i*64 + lane]));
          u16 h_ = f2bf(v);
          shx[(1+i)*PR + lane] = h_;
          slx[(1+i)*PR + lane] = f2bf(v - bf2f(h_));
        }
      }
      if (wid == 2 && kband < 63) {       // bottom margin <- down-neighbor's haloT
        int f = -1, guard = 0;
        while (f < e && ++guard < (1<<17)) {
          if (lane == 0) f = ATOM_LD(&ws->flags[g+1][0]);
          f = __shfl(f, 0);
          if (f < e) __builtin_amdgcn_s_sleep(1);
        }
        asm volatile("" ::: "memory");
#pragma unroll
        for (int i = 0; i < 4; ++i) {     // absr a+8+i -> slot 12+i
          float v = __uint_as_float(ATOM_LD(&ws->haloT[g+1][par][i*64 + lane]));
          u16 h_ = f2bf(v);
          shx[(12+i)*PR + lane] = h_;
          slx[(12+i)*PR + lane] = f2bf(v - bf2f(h_));
        }
      }
    }
    __syncthreads();   // margins + u primed before next epoch's first read
  }
}

extern "C" void kernel_launch(void* const* d_in, const int* in_sizes, int n_in,
                              void* d_out, int out_size, void* d_ws, size_t ws_size,
                              hipStream_t stream) {
  const float* feat = (const float*)d_in[0];
  const float* wih  = (const float*)d_in[1];
  const float* whh  = (const float*)d_in[2];
  const float* bih  = (const float*)d_in[3];
  const float* bhh  = (const float*)d_in[4];
  float* out = (float*)d_out;
  Ws* ws = (Ws*)d_ws;

  reset_flags<<<1, NWG, 0, stream>>>((int*)ws->flags);
  gru_scan<<<NWG, 256, 0, stream>>>(feat, wih, whh, bih, bhh, out, ws);
}

// Round 11
// 1278.290 us; speedup vs baseline: 2.9214x; 1.6388x over previous
//
#include <hip/hip_runtime.h>

typedef short short8 __attribute__((ext_vector_type(8)));
typedef float f32x4 __attribute__((ext_vector_type(4)));
typedef unsigned short u16;
typedef unsigned int u32;

#define C64 64
#define HWp (512*512)
#define NWG 256    // 4 images x 64 bands of 8 rows
#define PR 72      // LDS row stride in u16 (144 B)
#define SLOTS 18   // state window absrows a-5 .. a+12 (slot = absr-(a-5))
#define SBUF 2048  // u16 per state plane buffer (pow2 pad of 18*72=1296)
#define UBUF 2048  // u16 per u plane buffer (pow2 pad of 16*72=1152)
#define NEP 128    // 511 = 4*127 + 3

struct Ws {
  int flags[NWG][32];        // one 128B line per band
  u32 haloT[NWG][2][4*64];   // band's owned rows absr a..a+3   (m=4..7)
  u32 haloB[NWG][2][4*64];   // band's owned rows absr a+4..a+7 (m=8..11)
};

__device__ __forceinline__ u16 f2bf(float f){
  u32 r;
  asm("v_cvt_pk_bf16_f32 %0, %1, %1" : "=v"(r) : "v"(f));  // RNE, 1 instr
  return (u16)r;
}
__device__ __forceinline__ float bf2f(u16 h){ return __uint_as_float(((u32)h) << 16); }
__device__ __forceinline__ f32x4 splat4(float x){ f32x4 v = {x,x,x,x}; return v; }
__device__ __forceinline__ float sigm(float x){ return 1.f/(1.f + __expf(-x)); }
__device__ __forceinline__ float tanh_(float x){ float e = __expf(2.f*x); return 1.f - 2.f/(e + 1.f); }

#define MFMA16(a,b,c) __builtin_amdgcn_mfma_f32_16x16x32_bf16(a,b,c,0,0,0)
#define ATOM_ST(p,v) __hip_atomic_store((p),(v),__ATOMIC_RELAXED,__HIP_MEMORY_SCOPE_AGENT)
#define ATOM_LD(p)   __hip_atomic_load((p),__ATOMIC_RELAXED,__HIP_MEMORY_SCOPE_AGENT)
#define DOT3(acc, XH, XL, WH, WL) \
  acc = MFMA16(XH, WH, acc); acc = MFMA16(XL, WH, acc); acc = MFMA16(XH, WL, acc);

__global__ void reset_flags(int* flags) {
  if (threadIdx.x < NWG) flags[threadIdx.x * 32] = -1;
}

// ---- per-step building blocks (expanded with literal DD via enclosing enum) ----
#define AKK(kk) {                                                        \
  const int _o = PS + aoff + ((kk)>>1)*PR + ((kk)&1)*32;                 \
  short8 Ah = *(const short8*)&sh[_o];                                   \
  short8 Al = *(const short8*)&sl[_o];                                   \
  DOT3(aR, Ah, Al, BihH[0][kk], BihL[0][kk]);                            \
  DOT3(aZ, Ah, Al, BihH[1][kk], BihL[1][kk]);                            \
  DOT3(aI, Ah, Al, BihH[2][kk], BihL[2][kk]); }

#define XKT(kt) {                                                        \
  const int _o = PU + aoff + (kt)*32;                                    \
  short8 Xh = *(const short8*)&uh[_o];                                   \
  short8 Xl = *(const short8*)&ul[_o];                                   \
  DOT3(aR, Xh, Xl, BhhH[0][kt], BhhL[0][kt]);                            \
  DOT3(aZ, Xh, Xl, BhhH[1][kt], BhhL[1][kt]);                            \
  DOT3(aH, Xh, Xl, BhhH[2][kt], BhhL[2][kt]); }

#define GWB(j) {                                                         \
  const int m = kgrp*4 + (j);                                            \
  const int absr = a - 4 + m;                                            \
  float r = sigm(aR[j]);                                                 \
  float z = sigm(aZ[j]);                                                 \
  float nn = tanh_(aI[j] + r*aH[j]);                                     \
  float cur = bf2f(uh[PU + m*PR + ch]) + bf2f(ul[PU + m*PR + ch]);       \
  float v = (1.f - z)*nn + z*cur;                                        \
  if ((unsigned)absr < 512u) {                                           \
    u16 h_ = f2bf(v);                                                    \
    sh[PN + (m+1)*PR + ch] = h_;                                         \
    sl[PN + (m+1)*PR + ch] = f2bf(v - bf2f(h_));                         \
  }                                                                      \
  if (m >= 4 && m < 12) ost[((m-4)*64 + ch)*16 + dc0 + DD] = f2bf(v);    \
  if (DD == 3) {                                                         \
    if (kgrp == 1) ATOM_ST(&ws->haloT[g][e&1][(j)*64 + ch], __float_as_uint(v)); \
    if (kgrp == 2) ATOM_ST(&ws->haloB[g][e&1][(j)*64 + ch], __float_as_uint(v)); \
  } }

#define UST(i) {                                                         \
  float v = cv[DD][i];                                                   \
  u16 h_ = f2bf(v);                                                      \
  uh[PV + uoff[i]] = h_;                                                 \
  ul[PV + uoff[i]] = f2bf(v - bf2f(h_));                                 \
  cv[DD][i] = nv[i]; }

#define STEP(DD_) {                                                      \
  enum { DD = DD_, PS = (DD&1)*SBUF, PN = ((DD&1)^1)*SBUF,               \
         PU = (DD&1)*UBUF, PV = ((DD&1)^1)*UBUF };                       \
  float nv[4];                                                           \
  { int cc = 4*e + 6 + DD; if (cc > 511) cc = 511;                       \
    nv[0] = fval0 ? frow0[cc] : 0.f;                                     \
    nv[1] = fval1 ? frow1[cc] : 0.f;                                     \
    nv[2] = fval2 ? frow2[cc] : 0.f;                                     \
    nv[3] = fval3 ? frow3[cc] : 0.f; }                                   \
  f32x4 aR = splat4(biasR), aZ = splat4(biasZ);                          \
  f32x4 aI = splat4(biasI), aH = splat4(biasHn);                         \
  AKK(0) AKK(1) AKK(2) AKK(3) AKK(4) AKK(5)                              \
  XKT(0) XKT(1)                                                          \
  GWB(0) GWB(1) GWB(2) GWB(3)                                            \
  UST(0) UST(1) UST(2) UST(3)                                            \
}

__global__ __launch_bounds__(256, 1)
void gru_scan(const float* __restrict__ feat,
              const float* __restrict__ w_ih,
              const float* __restrict__ w_hh,
              const float* __restrict__ b_ih,
              const float* __restrict__ b_hh,
              float* __restrict__ out,
              Ws* __restrict__ ws)
{
  __shared__ __align__(16) u16 sh[2*SBUF], sl[2*SBUF];
  __shared__ __align__(16) u16 uh[2*UBUF], ul[2*UBUF];
  __shared__ __align__(16) u16 ost[8*64*16];   // [(row*64+ch)*16 + dc] bf16

  const int tid  = threadIdx.x;
  const int wgid = blockIdx.x;
  const int g    = (wgid & 7) * 32 + (wgid >> 3);   // XCD-local band chains
  const int b    = g >> 6;
  const int kband= g & 63;
  const int a    = kband * 8;
  const int lane = tid & 63;
  const int wid  = tid >> 6;
  const int ln16 = lane & 15;
  const int kgrp = lane >> 4;
  const int ch   = wid*16 + ln16;

  // ---- weights (hi+lo) in registers: 192 VGPR ----
  short8 BihH[3][6], BihL[3][6], BhhH[3][2], BhhL[3][2];
#pragma unroll
  for (int gg = 0; gg < 3; ++gg) {
    const int n = gg*64 + ch;
#pragma unroll
    for (int kk = 0; kk < 6; ++kk) {
      short8 vh, vl;
#pragma unroll
      for (int j = 0; j < 8; ++j) {
        float wv = w_ih[n*192 + kk*32 + kgrp*8 + j];
        u16 h = f2bf(wv); vh[j] = (short)h; vl[j] = (short)f2bf(wv - bf2f(h));
      }
      BihH[gg][kk] = vh; BihL[gg][kk] = vl;
    }
#pragma unroll
    for (int kt = 0; kt < 2; ++kt) {
      short8 vh, vl;
#pragma unroll
      for (int j = 0; j < 8; ++j) {
        float wv = w_hh[n*64 + kt*32 + kgrp*8 + j];
        u16 h = f2bf(wv); vh[j] = (short)h; vl[j] = (short)f2bf(wv - bf2f(h));
      }
      BhhH[gg][kt] = vh; BhhL[gg][kt] = vl;
    }
  }
  const float biasR  = b_ih[ch]       + b_hh[ch];
  const float biasZ  = b_ih[64 + ch]  + b_hh[64 + ch];
  const float biasI  = b_ih[128 + ch];
  const float biasHn = b_hh[128 + ch];

  // ---- static per-thread offsets ----
  const int aoff = ln16*PR + kgrp*8;              // A/X fragment base
  const int lch  = tid & 63;
  const int lr0  = wid * 4;                       // loader rows (u rows m=lr0..lr0+3)
  int uoff[4];
#pragma unroll
  for (int i = 0; i < 4; ++i) uoff[i] = (lr0 + i)*PR + lch;

  const float* fbase = feat + (size_t)(b*C64 + lch)*HWp;
  int ar0 = a - 4 + lr0;
  const bool fval0 = (unsigned)(ar0+0) < 512u;
  const bool fval1 = (unsigned)(ar0+1) < 512u;
  const bool fval2 = (unsigned)(ar0+2) < 512u;
  const bool fval3 = (unsigned)(ar0+3) < 512u;
  const float* frow0 = fbase + (size_t)(fval0 ? ar0+0 : 0)*512;
  const float* frow1 = fbase + (size_t)(fval1 ? ar0+1 : 0)*512;
  const float* frow2 = fbase + (size_t)(fval2 ? ar0+2 : 0)*512;
  const float* frow3 = fbase + (size_t)(fval3 ? ar0+3 : 0)*512;

  // ---- init ----
  for (int i = tid; i < 2*SBUF; i += 256) { sh[i] = 0; sl[i] = 0; }
  for (int i = tid; i < 2*UBUF; i += 256) { uh[i] = 0; ul[i] = 0; }
  __syncthreads();
  // feat col 0 -> state buf0 slots 0..17 + owned passthrough (slots 5..12)
#pragma unroll
  for (int i = 0; i < 5; ++i) {
    const int s = wid + 4*i;
    if (s < SLOTS) {
      const int absr = a - 5 + s;
      if ((unsigned)absr < 512u) {
        float v = fbase[(size_t)absr*512];
        u16 h_ = f2bf(v);
        sh[s*PR + lch] = h_;
        sl[s*PR + lch] = f2bf(v - bf2f(h_));
        if (s >= 5 && s <= 12) out[(size_t)(b*C64 + lch)*HWp + (size_t)absr*512] = v;
      }
    }
  }
  // u buf0 <- col 1; cv pipeline <- cols 2..5
  float cv[4][4];
#pragma unroll
  for (int i = 0; i < 4; ++i) {
    const int absr = a - 4 + lr0 + i;
    const bool val = (unsigned)absr < 512u;
    const float* fr = fbase + (size_t)(val ? absr : 0)*512;
    float v1 = val ? fr[1] : 0.f;
    u16 h_ = f2bf(v1);
    uh[uoff[i]] = h_;
    ul[uoff[i]] = f2bf(v1 - bf2f(h_));
    cv[0][i] = val ? fr[2] : 0.f;
    cv[1][i] = val ? fr[3] : 0.f;
    cv[2][i] = val ? fr[4] : 0.f;
    cv[3][i] = val ? fr[5] : 0.f;
  }
  __syncthreads();

  // ---- epoch loop: 4 columns per epoch, parity static (T even) ----
#pragma unroll 1
  for (int e = 0; e < NEP; ++e) {
    const int dc0 = (e & 3) * 4;
    STEP(0)
    __syncthreads();
    STEP(1)
    __syncthreads();
    STEP(2)
    if (e < NEP-1) {
      __syncthreads();
      STEP(3)
    }

    // ---- boundary ----
    asm volatile("s_waitcnt vmcnt(0)" ::: "memory");   // per-wave drain (halo sends)
    __syncthreads();
    if (e < NEP-1 && tid == 0) ATOM_ST(&ws->flags[g][0], e);

    if (wid == 0 || wid == 3) {
      if ((e & 3) == 3) {      // flush 16 finished columns, coalesced 64B/row
        const int t128  = (wid == 0) ? lane : 64 + lane;
        const int wbase = 4*(e-3) + 1;
#pragma unroll
        for (int i = 0; i < 4; ++i) {
          const int pi  = t128 + 128*i;      // row*64 + ch
          const int row = pi >> 6, c = pi & 63;
          float* go = out + (size_t)(b*C64 + c)*HWp + (size_t)(a + row)*512 + wbase;
#pragma unroll
          for (int dc = 0; dc < 16; ++dc)
            if (wbase + dc <= 511) go[dc] = bf2f(ost[pi*16 + dc]);
        }
      }
    } else if (e < NEP-1) {
      if (wid == 1 && kband > 0) {       // top margin <- g-1's haloB (absr a-4..a-1)
        int f = -1, guard = 0;
        while (f < e && ++guard < (1<<17)) {
          if (lane == 0) f = ATOM_LD(&ws->flags[g-1][0]);
          f = __shfl(f, 0);
          if (f < e) __builtin_amdgcn_s_sleep(1);
        }
        asm volatile("" ::: "memory");
#pragma unroll
        for (int i = 0; i < 4; ++i) {    // -> buf0 slot 1+i
          float v = __uint_as_float(ATOM_LD(&ws->haloB[g-1][e&1][i*64 + lane]));
          u16 h_ = f2bf(v);
          sh[(1+i)*PR + lane] = h_;
          sl[(1+i)*PR + lane] = f2bf(v - bf2f(h_));
        }
      }
      if (wid == 2 && kband < 63) {      // bottom margin <- g+1's haloT (absr a+8..a+11)
        int f = -1, guard = 0;
        while (f < e && ++guard < (1<<17)) {
          if (lane == 0) f = ATOM_LD(&ws->flags[g+1][0]);
          f = __shfl(f, 0);
          if (f < e) __builtin_amdgcn_s_sleep(1);
        }
        asm volatile("" ::: "memory");
#pragma unroll
        for (int i = 0; i < 4; ++i) {    // -> buf0 slot 13+i
          float v = __uint_as_float(ATOM_LD(&ws->haloT[g+1][e&1][i*64 + lane]));
          u16 h_ = f2bf(v);
          sh[(13+i)*PR + lane] = h_;
          sl[(13+i)*PR + lane] = f2bf(v - bf2f(h_));
        }
      }
    }
    __syncthreads();   // margins in buf0 + flush done before next epoch
  }
}

extern "C" void kernel_launch(void* const* d_in, const int* in_sizes, int n_in,
                              void* d_out, int out_size, void* d_ws, size_t ws_size,
                              hipStream_t stream) {
  const float* feat = (const float*)d_in[0];
  const float* wih  = (const float*)d_in[1];
  const float* whh  = (const float*)d_in[2];
  const float* bih  = (const float*)d_in[3];
  const float* bhh  = (const float*)d_in[4];
  float* out = (float*)d_out;
  Ws* ws = (Ws*)d_ws;

  reset_flags<<<1, NWG, 0, stream>>>((int*)ws->flags);
  gru_scan<<<NWG, 256, 0, stream>>>(feat, wih, whh, bih, bhh, out, ws);
}